// Round 19
// baseline (326.100 us; speedup 1.0000x reference)
//
#include <hip/hip_runtime.h>
#include <hip/hip_bf16.h>

#define NN 50000
#define NE 800000
#define HD 256
#define KIN 128
#define SCAN_B 49

#define FB_EDGE 3125    // 256 edges per 1024-thread block (16 waves x 16 edges)
#define FB_FEAT 391     // 4 x 32-node sub-blocks each (1564 sub-blocks >= 1563)
#define FB_FILL 256     // 4 x 256-thread sub-blocks each (1024 sub-blocks)

typedef __attribute__((ext_vector_type(8))) short bf16x8;
typedef __attribute__((ext_vector_type(8))) short short8v;
typedef __attribute__((ext_vector_type(4))) float f32x4;

static __device__ __forceinline__ short f2b(float f){
  union { __hip_bfloat16 h; short s; } u;
  u.h = __float2bfloat16(f);
  return u.s;
}
static __device__ __forceinline__ float b2f(short s){
  union { __hip_bfloat16 h; short s; } u;
  u.s = s;
  return __bfloat162float(u.h);
}
static __device__ __forceinline__ unsigned packbf(float a, float b){
  union { short s[2]; unsigned u; } z;
  z.s[0] = f2b(a); z.s[1] = f2b(b);
  return z.u;
}
static __device__ __forceinline__ bf16x8 cvt8(float4 x0, float4 x1){
  bf16x8 t;
  t[0]=f2b(x0.x); t[1]=f2b(x0.y); t[2]=f2b(x0.z); t[3]=f2b(x0.w);
  t[4]=f2b(x1.x); t[5]=f2b(x1.y); t[6]=f2b(x1.z); t[7]=f2b(x1.w);
  return t;
}
// softplus(x)-log(2) on raw v_exp/v_log
static __device__ __forceinline__ float sspf(float x){
#if __has_builtin(__builtin_amdgcn_exp2f) && __has_builtin(__builtin_amdgcn_logf)
  const float t = __builtin_amdgcn_exp2f(fabsf(x) * -1.4426950408889634f);
  return fmaf(__builtin_amdgcn_logf(1.0f + t) - 1.0f, 0.69314718055994531f, fmaxf(x, 0.0f));
#else
  const float t = __expf(-fabsf(x));
  return fmaxf(x, 0.0f) + __logf(1.0f + t) - 0.69314718055994531f;
#endif
}

// ---------- weight fp32 -> bf16 + packed epilogue table + degree histogram ----------
__global__ void k_cvh(const float* __restrict__ wfc, const float* __restrict__ we1,
                      const float* __restrict__ we2,
                      const float* __restrict__ be2, const float* __restrict__ attn_e,
                      const int* __restrict__ dst,
                      short* __restrict__ wfcb, short* __restrict__ we1b,
                      short* __restrict__ we2b, float* __restrict__ w2pk,
                      int* __restrict__ deg){
  const int i = blockIdx.x*256 + threadIdx.x;
  if (i < HD*KIN) wfcb[i] = f2b(wfc[i]);
  if (i < 32*KIN) we1b[i] = f2b(we1[i]);
  if (i < HD*32)  we2b[i] = f2b(we2[i]);
  if (i < 512){
    const int cht = i >> 5, r = i & 31, lq = r >> 3, j = r & 7;
    const int ch = cht*16 + lq*4 + (j & 3);
    w2pk[i] = (j < 4) ? be2[ch] : attn_e[ch];
  }
  for (int e = i; e < NE; e += gridDim.x*blockDim.x)
    atomicAdd(&deg[dst[e]], 1);
}

// ---------- CSR scan ----------
__global__ __launch_bounds__(1024) void k_scanA(const int* __restrict__ deg,
                                                int* __restrict__ bsum){
  __shared__ int ws[16];
  const int t = threadIdx.x;
  const int i = blockIdx.x*1024 + t;
  int v = (i < NN) ? deg[i] : 0;
#pragma unroll
  for (int m=1;m<64;m<<=1) v += __shfl_xor(v, m, 64);
  if ((t & 63) == 0) ws[t >> 6] = v;
  __syncthreads();
  if (t == 0){
    int s = 0;
#pragma unroll
    for (int k=0;k<16;++k) s += ws[k];
    bsum[blockIdx.x] = s;
  }
}

__global__ __launch_bounds__(1024) void k_scanC(const int* __restrict__ deg,
                                                const int* __restrict__ bsum,
                                                int* __restrict__ rowptr,
                                                int* __restrict__ fillptr){
  __shared__ int ws[16];
  __shared__ int boff_s, total_s;
  const int t = threadIdx.x, l = t & 63, wid = t >> 6;
  if (t < 64){
    const int v = (t < SCAN_B) ? bsum[t] : 0;
    int x = v;
#pragma unroll
    for (int off=1; off<64; off<<=1){
      const int y = __shfl_up(x, off, 64);
      if (t >= off) x += y;
    }
    if (t == (int)blockIdx.x) boff_s = x - v;
    if (t == SCAN_B-1) total_s = x;
  }
  __syncthreads();
  const int i = blockIdx.x*1024 + t;
  const int v = (i < NN) ? deg[i] : 0;
  int x = v;
#pragma unroll
  for (int off=1; off<64; off<<=1){
    const int y = __shfl_up(x, off, 64);
    if (l >= off) x += y;
  }
  if (l == 63) ws[wid] = x;
  __syncthreads();
  if (t == 0){
    int run = 0;
#pragma unroll
    for (int k=0;k<16;++k){ const int tmp = ws[k]; ws[k] = run; run += tmp; }
  }
  __syncthreads();
  if (i < NN){
    const int excl = boff_s + ws[wid] + (x - v);
    rowptr[i] = excl; fillptr[i] = excl;
  }
  if (blockIdx.x == 0 && t == 0) rowptr[NN] = total_s;
}

// ---------- feat branch: 32-node tile per 256-thread sub-block ----------
static __device__ __forceinline__ void feat_body(
    int bid, int tid,
    const float* __restrict__ nfeat, const short* __restrict__ wfcb,
    const float* __restrict__ attn_l, const float* __restrict__ attn_r,
    short* __restrict__ featb, float* __restrict__ el, float* __restrict__ er)
{
  const int n0 = bid * 32;
  if (n0 >= NN) return;
  const int w = tid >> 6, l = tid & 63, l15 = l & 15, lq = l >> 4;

  f32x4 acc[2][4];
#pragma unroll
  for (int a=0;a<2;++a)
#pragma unroll
    for (int b=0;b<4;++b) acc[a][b] = (f32x4)0.0f;

#pragma unroll
  for (int ks=0; ks<4; ++ks){
    const int k0 = ks*32 + lq*8;
    bf16x8 af[2];
#pragma unroll
    for (int tr=0; tr<2; ++tr){
      int row = n0 + tr*16 + l15;
      if (row >= NN) row = NN-1;
      const float4 x0 = *reinterpret_cast<const float4*>(nfeat + (size_t)row*KIN + k0);
      const float4 x1 = *reinterpret_cast<const float4*>(nfeat + (size_t)row*KIN + k0 + 4);
      af[tr] = cvt8(x0, x1);
    }
#pragma unroll
    for (int tc=0; tc<4; ++tc){
      const int c = w*64 + tc*16 + l15;
      const bf16x8 bfrag = *reinterpret_cast<const bf16x8*>(wfcb + c*KIN + k0);
#pragma unroll
      for (int tr=0; tr<2; ++tr)
        acc[tr][tc] = __builtin_amdgcn_mfma_f32_16x16x32_bf16(af[tr], bfrag, acc[tr][tc], 0,0,0);
    }
  }

  float alr[4], arr_[4];
#pragma unroll
  for (int tc=0;tc<4;++tc){
    const int c = w*64 + tc*16 + l15;
    alr[tc] = attn_l[c]; arr_[tc] = attn_r[c];
  }
  float pl[2][4][2], pr[2][4][2];
#pragma unroll
  for (int tr=0;tr<2;++tr)
#pragma unroll
    for (int j=0;j<4;++j){ pl[tr][j][0]=pl[tr][j][1]=0.f; pr[tr][j][0]=pr[tr][j][1]=0.f; }

#pragma unroll
  for (int tr=0;tr<2;++tr){
    const int rowb = tr*16 + lq*4;
#pragma unroll
    for (int tc=0;tc<4;++tc){
      const int c = w*64 + tc*16 + l15;
      const int h2 = tc>>1;
#pragma unroll
      for (int j=0;j<4;++j){
        const float v = acc[tr][tc][j];
        const int node = n0 + rowb + j;
        if (node < NN) featb[node*HD + c] = f2b(v);
        pl[tr][j][h2] += v*alr[tc];
        pr[tr][j][h2] += v*arr_[tc];
      }
    }
  }
#pragma unroll
  for (int m=1;m<16;m<<=1){
#pragma unroll
    for (int tr=0;tr<2;++tr)
#pragma unroll
      for (int j=0;j<4;++j){
        pl[tr][j][0] += __shfl_xor(pl[tr][j][0], m, 64);
        pl[tr][j][1] += __shfl_xor(pl[tr][j][1], m, 64);
        pr[tr][j][0] += __shfl_xor(pr[tr][j][0], m, 64);
        pr[tr][j][1] += __shfl_xor(pr[tr][j][1], m, 64);
      }
  }
#pragma unroll
  for (int tr=0;tr<2;++tr)
#pragma unroll
    for (int j=0;j<4;++j)
      if (l15 == tr*4+j){
        const int node = n0 + tr*16 + lq*4 + j;
        if (node < NN){
          el[node*8 + 2*w + 0] = pl[tr][j][0];
          el[node*8 + 2*w + 1] = pl[tr][j][1];
          er[node*8 + 2*w + 0] = pr[tr][j][0];
          er[node*8 + 2*w + 1] = pr[tr][j][1];
        }
      }
}

// ---------- fill branch (256-thread sub-block; 1024 sub-blocks total) ----------
static __device__ __forceinline__ void fill_body(
    int bid, int tid,
    const int* __restrict__ dst, const int* __restrict__ src,
    int* __restrict__ fillptr, int2* __restrict__ esrc)
{
  for (int i = bid*256 + tid; i < NE; i += 1024*256){
    const int p = atomicAdd(&fillptr[dst[i]], 1);
    esrc[p] = make_int2(i, src[i]);
  }
}

// ---------- edge branch: 16 edges/wave; GEMM2 weights+epilogue from LDS;
// GEMM2 2-way interleaved (cht, cht+8) for chain-level ILP ----------
static __device__ __forceinline__ void edge_body(
    int e0w, int l,
    const float* __restrict__ efeat, const float* __restrict__ rij,
    const short* __restrict__ we1b, const float* __restrict__ be1,
    const short* __restrict__ we2_lds, const float* __restrict__ pk_lds,
    float* __restrict__ ee)
{
  const int l15 = l & 15, lq = l >> 4;

  const float* erow = efeat + (size_t)(e0w + l15)*KIN + lq*8;
  const float4 r0 = *reinterpret_cast<const float4*>(erow);
  const float4 r1 = *reinterpret_cast<const float4*>(erow + 4);
  const float4 r2 = *reinterpret_cast<const float4*>(erow + 32);
  const float4 r3 = *reinterpret_cast<const float4*>(erow + 36);
  const float4 r4 = *reinterpret_cast<const float4*>(erow + 64);
  const float4 r5 = *reinterpret_cast<const float4*>(erow + 68);
  const float4 r6 = *reinterpret_cast<const float4*>(erow + 96);
  const float4 r7 = *reinterpret_cast<const float4*>(erow + 100);
  const float rv = rij[e0w + l15];

  f32x4 acc_t0 = (f32x4)0.0f, acc_t1 = (f32x4)0.0f;
  float4 raw[8] = {r0,r1,r2,r3,r4,r5,r6,r7};
#pragma unroll
  for (int ks=0; ks<4; ++ks){
    const int k0 = ks*32 + lq*8;
    const bf16x8 bfr = cvt8(raw[2*ks], raw[2*ks+1]);
    const bf16x8 a0 = *reinterpret_cast<const bf16x8*>(we1b + (l15     )*KIN + k0);
    const bf16x8 a1 = *reinterpret_cast<const bf16x8*>(we1b + (16 + l15)*KIN + k0);
    acc_t0 = __builtin_amdgcn_mfma_f32_16x16x32_bf16(a0, bfr, acc_t0, 0,0,0);
    acc_t1 = __builtin_amdgcn_mfma_f32_16x16x32_bf16(a1, bfr, acc_t1, 0,0,0);
  }

  const f32x4 b1a = *reinterpret_cast<const f32x4*>(be1 + lq*4);
  const f32x4 b1b = *reinterpret_cast<const f32x4*>(be1 + 16 + lq*4);
  const unsigned t0lo = packbf(sspf(acc_t0[0]+b1a[0]), sspf(acc_t0[1]+b1a[1]));
  const unsigned t0hi = packbf(sspf(acc_t0[2]+b1a[2]), sspf(acc_t0[3]+b1a[3]));
  const unsigned t1lo = packbf(sspf(acc_t1[0]+b1b[0]), sspf(acc_t1[1]+b1b[1]));
  const unsigned t1hi = packbf(sspf(acc_t1[2]+b1b[2]), sspf(acc_t1[3]+b1b[3]));

  const int srcA = ((lq & 1) << 5) + l15;
  const int srcB = srcA + 16;
  const int a_lo0 = __shfl((int)t0lo, srcA, 64), a_hi0 = __shfl((int)t0hi, srcA, 64);
  const int b_lo0 = __shfl((int)t0lo, srcB, 64), b_hi0 = __shfl((int)t0hi, srcB, 64);
  const int a_lo1 = __shfl((int)t1lo, srcA, 64), a_hi1 = __shfl((int)t1hi, srcA, 64);
  const int b_lo1 = __shfl((int)t1lo, srcB, 64), b_hi1 = __shfl((int)t1hi, srcB, 64);
  const bool th1sel = (lq & 2);
  union { int u[4]; bf16x8 v; } bx;
  bx.u[0] = th1sel ? a_lo1 : a_lo0;
  bx.u[1] = th1sel ? a_hi1 : a_hi0;
  bx.u[2] = th1sel ? b_lo1 : b_lo0;
  bx.u[3] = th1sel ? b_hi1 : b_hi0;

  const float* pkb = pk_lds + lq*8;
  const short* w2b = we2_lds + ((lq*256 + l15) * 8);
  float pe[8];
#pragma unroll
  for (int h=0;h<8;++h) pe[h] = 0.f;
  // 2-way interleave: iterations cht and cht+8 are independent chains
#pragma unroll
  for (int cht=0; cht<8; ++cht){
    const bf16x8 a2A = *reinterpret_cast<const bf16x8*>(w2b + cht*128);
    const bf16x8 a2B = *reinterpret_cast<const bf16x8*>(w2b + (cht+8)*128);
    const f32x4 dA = __builtin_amdgcn_mfma_f32_16x16x32_bf16(a2A, bx.v, (f32x4)0.0f, 0,0,0);
    const f32x4 dB = __builtin_amdgcn_mfma_f32_16x16x32_bf16(a2B, bx.v, (f32x4)0.0f, 0,0,0);
    const f32x4 b2A = *reinterpret_cast<const f32x4*>(pkb + cht*32);
    const f32x4 aeA = *reinterpret_cast<const f32x4*>(pkb + cht*32 + 4);
    const f32x4 b2B = *reinterpret_cast<const f32x4*>(pkb + (cht+8)*32);
    const f32x4 aeB = *reinterpret_cast<const f32x4*>(pkb + (cht+8)*32 + 4);
    float sA = 0.f, sB = 0.f;
#pragma unroll
    for (int j=0;j<4;++j){
      sA = fmaf(sspf(dA[j] + b2A[j]), aeA[j], sA);
      sB = fmaf(sspf(dB[j] + b2B[j]), aeB[j], sB);
    }
    pe[cht>>1]     += sA;
    pe[(cht+8)>>1] += sB;
  }
#pragma unroll
  for (int h=0;h<8;++h){
    pe[h] += __shfl_xor(pe[h], 16, 64);
    pe[h] += __shfl_xor(pe[h], 32, 64);
  }
  const float fcv = (rv < 5.0f) ? 0.5f*(__cosf(0.62831853071795864f*rv) + 1.0f) : 0.0f;
  const float o0 = (lq==0) ? pe[0] : (lq==1) ? pe[2] : (lq==2) ? pe[4] : pe[6];
  const float o1 = (lq==0) ? pe[1] : (lq==1) ? pe[3] : (lq==2) ? pe[5] : pe[7];
  float2 outv; outv.x = o0*fcv; outv.y = o1*fcv;
  *reinterpret_cast<float2*>(ee + (size_t)(e0w + l15)*8 + lq*2) = outv;
}

// ---------- FAT kernel (1024 threads): edge | feat | fill ----------
__global__ __launch_bounds__(1024) void k_big(
    const float* __restrict__ nfeat, const short* __restrict__ wfcb,
    const float* __restrict__ attn_l, const float* __restrict__ attn_r,
    short* __restrict__ featb, float* __restrict__ el, float* __restrict__ er,
    const int* __restrict__ dst, const int* __restrict__ src,
    int* __restrict__ fillptr, int2* __restrict__ esrc,
    const float* __restrict__ efeat, const float* __restrict__ rij,
    const short* __restrict__ we1b, const float* __restrict__ be1,
    const short* __restrict__ we2b, const float* __restrict__ w2pk,
    float* __restrict__ ee)
{
  __shared__ __align__(16) short we2_lds[4*256*8];  // 16 KB, lq-plane layout
  __shared__ __align__(16) float pk_lds[512];       // 2 KB
  const int bid = blockIdx.x, tid = threadIdx.x;
  if (bid < FB_EDGE){
    // cooperative stage across 1024 threads: thread t stages 1 plane-row
    {
      const int plane = tid >> 8, ch = tid & 255;
      const short* g = we2b + ch*32 + plane*8;
      const short8v q = *reinterpret_cast<const short8v*>(g);
      *reinterpret_cast<short8v*>(&we2_lds[(plane*256 + ch)*8]) = q;
      if (tid < 512) pk_lds[tid] = w2pk[tid];
    }
    __syncthreads();
    const int w = tid >> 6;                         // 16 waves
    edge_body(bid*256 + w*16, tid & 63, efeat, rij, we1b, be1, we2_lds, pk_lds, ee);
  } else if (bid < FB_EDGE + FB_FEAT){
    const int sub = tid >> 8;                       // four 32-node sub-blocks
    feat_body((bid - FB_EDGE)*4 + sub, tid & 255, nfeat, wfcb, attn_l, attn_r,
              featb, el, er);
  } else {
    const int sub = tid >> 8;
    fill_body((bid - FB_EDGE - FB_FEAT)*4 + sub, tid & 255, dst, src, fillptr, esrc);
  }
}

// ---------- SINGLE-PASS softmax+aggregation: wave per node ----------
__global__ __launch_bounds__(256) void k_sa(
    const int* __restrict__ rowptr, const int2* __restrict__ esrc,
    const float* __restrict__ el, const float* __restrict__ er,
    const float* __restrict__ ee, const short* __restrict__ featb,
    const float* __restrict__ bias, float* __restrict__ out)
{
  const int t = threadIdx.x, l = t & 63, w = t >> 6;
  const int n = blockIdx.x*4 + w;
  const int beg = rowptr[n], end = rowptr[n+1];
  const int stream = l >> 5, cl = l & 31, hh = cl >> 2;
  const float er_hh = er[(size_t)n*8 + hh];

  float acc[8];
#pragma unroll
  for (int k=0;k<8;++k) acc[k] = 0.f;
  float s = 0.f;
  for (int p = beg + stream; p < end; p += 2){
    const int2 es = esrc[p];
    const float x = ee[(size_t)es.x*8 + hh];
    float e = x + el[(size_t)es.y*8 + hh] + er_hh;
    e = e > 0.f ? e : 0.2f*e;
    const float pex = __expf(e);
    const float c = pex * x;
    s += pex;
    const short8v fv = *reinterpret_cast<const short8v*>(featb + (size_t)es.y*HD + cl*8);
#pragma unroll
    for (int k=0;k<8;++k) acc[k] = fmaf(c, b2f(fv[k]), acc[k]);
  }
  s += __shfl_xor(s, 32, 64);
#pragma unroll
  for (int k=0;k<8;++k) acc[k] += __shfl_xor(acc[k], 32, 64);
  if (l < 32){
    const float inv = (s > 0.f) ? 1.0f / s : 0.0f;
    const float4 b0 = *reinterpret_cast<const float4*>(bias + cl*8);
    const float4 b1 = *reinterpret_cast<const float4*>(bias + cl*8 + 4);
    float4 o0, o1;
    o0.x=fmaf(acc[0],inv,b0.x); o0.y=fmaf(acc[1],inv,b0.y);
    o0.z=fmaf(acc[2],inv,b0.z); o0.w=fmaf(acc[3],inv,b0.w);
    o1.x=fmaf(acc[4],inv,b1.x); o1.y=fmaf(acc[5],inv,b1.y);
    o1.z=fmaf(acc[6],inv,b1.z); o1.w=fmaf(acc[7],inv,b1.w);
    *reinterpret_cast<float4*>(out + (size_t)n*HD + cl*8) = o0;
    *reinterpret_cast<float4*>(out + (size_t)n*HD + cl*8 + 4) = o1;
  }
}

extern "C" void kernel_launch(void* const* d_in, const int* in_sizes, int n_in,
                              void* d_out, int out_size, void* d_ws, size_t ws_size,
                              hipStream_t stream) {
  const float* nfeat  = (const float*)d_in[0];
  const float* efeat  = (const float*)d_in[1];
  const float* rij    = (const float*)d_in[2];
  const int*   src    = (const int*)d_in[3];
  const int*   dst    = (const int*)d_in[4];
  const float* W_fc   = (const float*)d_in[5];
  const float* W_e1   = (const float*)d_in[6];
  const float* b_e1   = (const float*)d_in[7];
  const float* W_e2   = (const float*)d_in[8];
  const float* b_e2   = (const float*)d_in[9];
  const float* attn_l = (const float*)d_in[10];
  const float* attn_r = (const float*)d_in[11];
  const float* attn_e = (const float*)d_in[12];
  const float* bias   = (const float*)d_in[13];
  float* out = (float*)d_out;

  size_t off = 0;
  auto carve = [&](size_t nbytes) -> void* {
    void* p = (char*)d_ws + off;
    off += (nbytes + 255) & ~(size_t)255;
    return p;
  };
  short* featb = (short*)carve((size_t)NN*HD*2);
  float* el    = (float*)carve((size_t)NN*8*4);
  float* er    = (float*)carve((size_t)NN*8*4);
  float* ee    = (float*)carve((size_t)NE*8*4);
  int* deg     = (int*)carve((size_t)NN*4);
  int* rowptr  = (int*)carve((size_t)(NN+1)*4);
  int* fillptr = (int*)carve((size_t)(NN+1)*4);
  int2* esrc   = (int2*)carve((size_t)NE*8);
  int* bsum    = (int*)carve((size_t)SCAN_B*4);
  short* wfcb  = (short*)carve((size_t)HD*KIN*2);
  short* we1b  = (short*)carve((size_t)32*KIN*2);
  short* we2b  = (short*)carve((size_t)HD*32*2);
  float* w2pk  = (float*)carve((size_t)512*4);

  hipMemsetAsync(deg, 0, (size_t)NN*4, stream);
  k_cvh<<<1024, 256, 0, stream>>>(W_fc, W_e1, W_e2, b_e2, attn_e, dst,
                                  wfcb, we1b, we2b, w2pk, deg);
  k_scanA<<<SCAN_B, 1024, 0, stream>>>(deg, bsum);
  k_scanC<<<SCAN_B, 1024, 0, stream>>>(deg, bsum, rowptr, fillptr);
  k_big<<<FB_EDGE + FB_FEAT + FB_FILL, 1024, 0, stream>>>(
      nfeat, wfcb, attn_l, attn_r, featb, el, er,
      dst, src, fillptr, esrc,
      efeat, rij, we1b, b_e1, we2b, w2pk, ee);
  k_sa<<<(NN+3)/4, 256, 0, stream>>>(rowptr, esrc, el, er, ee, featb, bias, out);
}

// Round 20
// 313.249 us; speedup vs baseline: 1.0410x; 1.0410x over previous
//
#include <hip/hip_runtime.h>
#include <hip/hip_bf16.h>

#define NN 50000
#define NE 800000
#define HD 256
#define KIN 128
#define SCAN_B 49

#define FB_EDGE 6250    // 128 edges per 512-thread block (8 waves x 16 edges)
#define FB_FEAT 782     // 64 nodes per block (2 x 32-node sub-blocks)
#define FB_FILL 512     // 2 x 256-thread sub-blocks each

typedef __attribute__((ext_vector_type(8))) short bf16x8;
typedef __attribute__((ext_vector_type(8))) short short8v;
typedef __attribute__((ext_vector_type(4))) float f32x4;

static __device__ __forceinline__ short f2b(float f){
  union { __hip_bfloat16 h; short s; } u;
  u.h = __float2bfloat16(f);
  return u.s;
}
static __device__ __forceinline__ float b2f(short s){
  union { __hip_bfloat16 h; short s; } u;
  u.s = s;
  return __bfloat162float(u.h);
}
static __device__ __forceinline__ unsigned packbf(float a, float b){
  union { short s[2]; unsigned u; } z;
  z.s[0] = f2b(a); z.s[1] = f2b(b);
  return z.u;
}
static __device__ __forceinline__ bf16x8 cvt8(float4 x0, float4 x1){
  bf16x8 t;
  t[0]=f2b(x0.x); t[1]=f2b(x0.y); t[2]=f2b(x0.z); t[3]=f2b(x0.w);
  t[4]=f2b(x1.x); t[5]=f2b(x1.y); t[6]=f2b(x1.z); t[7]=f2b(x1.w);
  return t;
}
// softplus(x)-log(2) on raw v_exp/v_log
static __device__ __forceinline__ float sspf(float x){
#if __has_builtin(__builtin_amdgcn_exp2f) && __has_builtin(__builtin_amdgcn_logf)
  const float t = __builtin_amdgcn_exp2f(fabsf(x) * -1.4426950408889634f);
  return fmaf(__builtin_amdgcn_logf(1.0f + t) - 1.0f, 0.69314718055994531f, fmaxf(x, 0.0f));
#else
  const float t = __expf(-fabsf(x));
  return fmaxf(x, 0.0f) + __logf(1.0f + t) - 0.69314718055994531f;
#endif
}

// ---------- weight fp32 -> bf16 + packed epilogue table + degree histogram ----------
__global__ void k_cvh(const float* __restrict__ wfc, const float* __restrict__ we1,
                      const float* __restrict__ we2,
                      const float* __restrict__ be2, const float* __restrict__ attn_e,
                      const int* __restrict__ dst,
                      short* __restrict__ wfcb, short* __restrict__ we1b,
                      short* __restrict__ we2b, float* __restrict__ w2pk,
                      int* __restrict__ deg){
  const int i = blockIdx.x*256 + threadIdx.x;
  if (i < HD*KIN) wfcb[i] = f2b(wfc[i]);
  if (i < 32*KIN) we1b[i] = f2b(we1[i]);
  if (i < HD*32)  we2b[i] = f2b(we2[i]);
  if (i < 512){
    const int cht = i >> 5, r = i & 31, lq = r >> 3, j = r & 7;
    const int ch = cht*16 + lq*4 + (j & 3);
    w2pk[i] = (j < 4) ? be2[ch] : attn_e[ch];
  }
  for (int e = i; e < NE; e += gridDim.x*blockDim.x)
    atomicAdd(&deg[dst[e]], 1);
}

// ---------- CSR scan ----------
__global__ __launch_bounds__(1024) void k_scanA(const int* __restrict__ deg,
                                                int* __restrict__ bsum){
  __shared__ int ws[16];
  const int t = threadIdx.x;
  const int i = blockIdx.x*1024 + t;
  int v = (i < NN) ? deg[i] : 0;
#pragma unroll
  for (int m=1;m<64;m<<=1) v += __shfl_xor(v, m, 64);
  if ((t & 63) == 0) ws[t >> 6] = v;
  __syncthreads();
  if (t == 0){
    int s = 0;
#pragma unroll
    for (int k=0;k<16;++k) s += ws[k];
    bsum[blockIdx.x] = s;
  }
}

__global__ __launch_bounds__(1024) void k_scanC(const int* __restrict__ deg,
                                                const int* __restrict__ bsum,
                                                int* __restrict__ rowptr,
                                                int* __restrict__ fillptr){
  __shared__ int ws[16];
  __shared__ int boff_s, total_s;
  const int t = threadIdx.x, l = t & 63, wid = t >> 6;
  if (t < 64){
    const int v = (t < SCAN_B) ? bsum[t] : 0;
    int x = v;
#pragma unroll
    for (int off=1; off<64; off<<=1){
      const int y = __shfl_up(x, off, 64);
      if (t >= off) x += y;
    }
    if (t == (int)blockIdx.x) boff_s = x - v;
    if (t == SCAN_B-1) total_s = x;
  }
  __syncthreads();
  const int i = blockIdx.x*1024 + t;
  const int v = (i < NN) ? deg[i] : 0;
  int x = v;
#pragma unroll
  for (int off=1; off<64; off<<=1){
    const int y = __shfl_up(x, off, 64);
    if (l >= off) x += y;
  }
  if (l == 63) ws[wid] = x;
  __syncthreads();
  if (t == 0){
    int run = 0;
#pragma unroll
    for (int k=0;k<16;++k){ const int tmp = ws[k]; ws[k] = run; run += tmp; }
  }
  __syncthreads();
  if (i < NN){
    const int excl = boff_s + ws[wid] + (x - v);
    rowptr[i] = excl; fillptr[i] = excl;
  }
  if (blockIdx.x == 0 && t == 0) rowptr[NN] = total_s;
}

// ---------- feat branch: 32-node tile per 256-thread sub-block ----------
static __device__ __forceinline__ void feat_body(
    int bid, int tid,
    const float* __restrict__ nfeat, const short* __restrict__ wfcb,
    const float* __restrict__ attn_l, const float* __restrict__ attn_r,
    short* __restrict__ featb, float* __restrict__ el, float* __restrict__ er)
{
  const int n0 = bid * 32;
  const int w = tid >> 6, l = tid & 63, l15 = l & 15, lq = l >> 4;

  f32x4 acc[2][4];
#pragma unroll
  for (int a=0;a<2;++a)
#pragma unroll
    for (int b=0;b<4;++b) acc[a][b] = (f32x4)0.0f;

#pragma unroll
  for (int ks=0; ks<4; ++ks){
    const int k0 = ks*32 + lq*8;
    bf16x8 af[2];
#pragma unroll
    for (int tr=0; tr<2; ++tr){
      int row = n0 + tr*16 + l15;
      if (row >= NN) row = NN-1;
      const float4 x0 = *reinterpret_cast<const float4*>(nfeat + (size_t)row*KIN + k0);
      const float4 x1 = *reinterpret_cast<const float4*>(nfeat + (size_t)row*KIN + k0 + 4);
      af[tr] = cvt8(x0, x1);
    }
#pragma unroll
    for (int tc=0; tc<4; ++tc){
      const int c = w*64 + tc*16 + l15;
      const bf16x8 bfrag = *reinterpret_cast<const bf16x8*>(wfcb + c*KIN + k0);
#pragma unroll
      for (int tr=0; tr<2; ++tr)
        acc[tr][tc] = __builtin_amdgcn_mfma_f32_16x16x32_bf16(af[tr], bfrag, acc[tr][tc], 0,0,0);
    }
  }

  float alr[4], arr_[4];
#pragma unroll
  for (int tc=0;tc<4;++tc){
    const int c = w*64 + tc*16 + l15;
    alr[tc] = attn_l[c]; arr_[tc] = attn_r[c];
  }
  float pl[2][4][2], pr[2][4][2];
#pragma unroll
  for (int tr=0;tr<2;++tr)
#pragma unroll
    for (int j=0;j<4;++j){ pl[tr][j][0]=pl[tr][j][1]=0.f; pr[tr][j][0]=pr[tr][j][1]=0.f; }

#pragma unroll
  for (int tr=0;tr<2;++tr){
    const int rowb = tr*16 + lq*4;
#pragma unroll
    for (int tc=0;tc<4;++tc){
      const int c = w*64 + tc*16 + l15;
      const int h2 = tc>>1;
#pragma unroll
      for (int j=0;j<4;++j){
        const float v = acc[tr][tc][j];
        const int node = n0 + rowb + j;
        if (node < NN) featb[node*HD + c] = f2b(v);
        pl[tr][j][h2] += v*alr[tc];
        pr[tr][j][h2] += v*arr_[tc];
      }
    }
  }
#pragma unroll
  for (int m=1;m<16;m<<=1){
#pragma unroll
    for (int tr=0;tr<2;++tr)
#pragma unroll
      for (int j=0;j<4;++j){
        pl[tr][j][0] += __shfl_xor(pl[tr][j][0], m, 64);
        pl[tr][j][1] += __shfl_xor(pl[tr][j][1], m, 64);
        pr[tr][j][0] += __shfl_xor(pr[tr][j][0], m, 64);
        pr[tr][j][1] += __shfl_xor(pr[tr][j][1], m, 64);
      }
  }
#pragma unroll
  for (int tr=0;tr<2;++tr)
#pragma unroll
    for (int j=0;j<4;++j)
      if (l15 == tr*4+j){
        const int node = n0 + tr*16 + lq*4 + j;
        if (node < NN){
          el[node*8 + 2*w + 0] = pl[tr][j][0];
          el[node*8 + 2*w + 1] = pl[tr][j][1];
          er[node*8 + 2*w + 0] = pr[tr][j][0];
          er[node*8 + 2*w + 1] = pr[tr][j][1];
        }
      }
}

// ---------- fill branch (256-thread sub-block; 1024 sub-blocks total) ----------
static __device__ __forceinline__ void fill_body(
    int bid, int tid,
    const int* __restrict__ dst, const int* __restrict__ src,
    int* __restrict__ fillptr, int2* __restrict__ esrc)
{
  for (int i = bid*256 + tid; i < NE; i += 1024*256){
    const int p = atomicAdd(&fillptr[dst[i]], 1);
    esrc[p] = make_int2(i, src[i]);
  }
}

// ---------- edge branch: 16 edges/wave; GEMM2 weights+epilogue from LDS;
// GEMM2 2-way interleaved (cht, cht+8) for chain-level ILP ----------
static __device__ __forceinline__ void edge_body(
    int e0w, int l,
    const float* __restrict__ efeat, const float* __restrict__ rij,
    const short* __restrict__ we1b, const float* __restrict__ be1,
    const short* __restrict__ we2_lds, const float* __restrict__ pk_lds,
    float* __restrict__ ee)
{
  const int l15 = l & 15, lq = l >> 4;

  const float* erow = efeat + (size_t)(e0w + l15)*KIN + lq*8;
  const float4 r0 = *reinterpret_cast<const float4*>(erow);
  const float4 r1 = *reinterpret_cast<const float4*>(erow + 4);
  const float4 r2 = *reinterpret_cast<const float4*>(erow + 32);
  const float4 r3 = *reinterpret_cast<const float4*>(erow + 36);
  const float4 r4 = *reinterpret_cast<const float4*>(erow + 64);
  const float4 r5 = *reinterpret_cast<const float4*>(erow + 68);
  const float4 r6 = *reinterpret_cast<const float4*>(erow + 96);
  const float4 r7 = *reinterpret_cast<const float4*>(erow + 100);
  const float rv = rij[e0w + l15];

  f32x4 acc_t0 = (f32x4)0.0f, acc_t1 = (f32x4)0.0f;
  float4 raw[8] = {r0,r1,r2,r3,r4,r5,r6,r7};
#pragma unroll
  for (int ks=0; ks<4; ++ks){
    const int k0 = ks*32 + lq*8;
    const bf16x8 bfr = cvt8(raw[2*ks], raw[2*ks+1]);
    const bf16x8 a0 = *reinterpret_cast<const bf16x8*>(we1b + (l15     )*KIN + k0);
    const bf16x8 a1 = *reinterpret_cast<const bf16x8*>(we1b + (16 + l15)*KIN + k0);
    acc_t0 = __builtin_amdgcn_mfma_f32_16x16x32_bf16(a0, bfr, acc_t0, 0,0,0);
    acc_t1 = __builtin_amdgcn_mfma_f32_16x16x32_bf16(a1, bfr, acc_t1, 0,0,0);
  }

  const f32x4 b1a = *reinterpret_cast<const f32x4*>(be1 + lq*4);
  const f32x4 b1b = *reinterpret_cast<const f32x4*>(be1 + 16 + lq*4);
  const unsigned t0lo = packbf(sspf(acc_t0[0]+b1a[0]), sspf(acc_t0[1]+b1a[1]));
  const unsigned t0hi = packbf(sspf(acc_t0[2]+b1a[2]), sspf(acc_t0[3]+b1a[3]));
  const unsigned t1lo = packbf(sspf(acc_t1[0]+b1b[0]), sspf(acc_t1[1]+b1b[1]));
  const unsigned t1hi = packbf(sspf(acc_t1[2]+b1b[2]), sspf(acc_t1[3]+b1b[3]));

  const int srcA = ((lq & 1) << 5) + l15;
  const int srcB = srcA + 16;
  const int a_lo0 = __shfl((int)t0lo, srcA, 64), a_hi0 = __shfl((int)t0hi, srcA, 64);
  const int b_lo0 = __shfl((int)t0lo, srcB, 64), b_hi0 = __shfl((int)t0hi, srcB, 64);
  const int a_lo1 = __shfl((int)t1lo, srcA, 64), a_hi1 = __shfl((int)t1hi, srcA, 64);
  const int b_lo1 = __shfl((int)t1lo, srcB, 64), b_hi1 = __shfl((int)t1hi, srcB, 64);
  const bool th1sel = (lq & 2);
  union { int u[4]; bf16x8 v; } bx;
  bx.u[0] = th1sel ? a_lo1 : a_lo0;
  bx.u[1] = th1sel ? a_hi1 : a_hi0;
  bx.u[2] = th1sel ? b_lo1 : b_lo0;
  bx.u[3] = th1sel ? b_hi1 : b_hi0;

  const float* pkb = pk_lds + lq*8;
  const short* w2b = we2_lds + ((lq*256 + l15) * 8);
  float pe[8];
#pragma unroll
  for (int h=0;h<8;++h) pe[h] = 0.f;
  // 2-way interleave: iterations cht and cht+8 are independent chains
#pragma unroll
  for (int cht=0; cht<8; ++cht){
    const bf16x8 a2A = *reinterpret_cast<const bf16x8*>(w2b + cht*128);
    const bf16x8 a2B = *reinterpret_cast<const bf16x8*>(w2b + (cht+8)*128);
    const f32x4 dA = __builtin_amdgcn_mfma_f32_16x16x32_bf16(a2A, bx.v, (f32x4)0.0f, 0,0,0);
    const f32x4 dB = __builtin_amdgcn_mfma_f32_16x16x32_bf16(a2B, bx.v, (f32x4)0.0f, 0,0,0);
    const f32x4 b2A = *reinterpret_cast<const f32x4*>(pkb + cht*32);
    const f32x4 aeA = *reinterpret_cast<const f32x4*>(pkb + cht*32 + 4);
    const f32x4 b2B = *reinterpret_cast<const f32x4*>(pkb + (cht+8)*32);
    const f32x4 aeB = *reinterpret_cast<const f32x4*>(pkb + (cht+8)*32 + 4);
    float sA = 0.f, sB = 0.f;
#pragma unroll
    for (int j=0;j<4;++j){
      sA = fmaf(sspf(dA[j] + b2A[j]), aeA[j], sA);
      sB = fmaf(sspf(dB[j] + b2B[j]), aeB[j], sB);
    }
    pe[cht>>1]     += sA;
    pe[(cht+8)>>1] += sB;
  }
#pragma unroll
  for (int h=0;h<8;++h){
    pe[h] += __shfl_xor(pe[h], 16, 64);
    pe[h] += __shfl_xor(pe[h], 32, 64);
  }
  const float fcv = (rv < 5.0f) ? 0.5f*(__cosf(0.62831853071795864f*rv) + 1.0f) : 0.0f;
  const float o0 = (lq==0) ? pe[0] : (lq==1) ? pe[2] : (lq==2) ? pe[4] : pe[6];
  const float o1 = (lq==0) ? pe[1] : (lq==1) ? pe[3] : (lq==2) ? pe[5] : pe[7];
  float2 outv; outv.x = o0*fcv; outv.y = o1*fcv;
  *reinterpret_cast<float2*>(ee + (size_t)(e0w + l15)*8 + lq*2) = outv;
}

// ---------- FAT kernel (512 threads): edge | feat | fill ----------
__global__ __launch_bounds__(512) void k_big(
    const float* __restrict__ nfeat, const short* __restrict__ wfcb,
    const float* __restrict__ attn_l, const float* __restrict__ attn_r,
    short* __restrict__ featb, float* __restrict__ el, float* __restrict__ er,
    const int* __restrict__ dst, const int* __restrict__ src,
    int* __restrict__ fillptr, int2* __restrict__ esrc,
    const float* __restrict__ efeat, const float* __restrict__ rij,
    const short* __restrict__ we1b, const float* __restrict__ be1,
    const short* __restrict__ we2b, const float* __restrict__ w2pk,
    float* __restrict__ ee)
{
  __shared__ __align__(16) short we2_lds[4*256*8];  // 16 KB, lq-plane layout
  __shared__ __align__(16) float pk_lds[512];       // 2 KB
  const int bid = blockIdx.x, tid = threadIdx.x;
  if (bid < FB_EDGE){
    // cooperative stage across 512 threads: thread t stages 2 planes of row (t&255)
    {
      const int ch = tid & 255, half = tid >> 8;   // half in {0,1}
      const short* g = we2b + ch*32 + half*16;
      const short8v q0 = *reinterpret_cast<const short8v*>(g);
      const short8v q1 = *reinterpret_cast<const short8v*>(g + 8);
      *reinterpret_cast<short8v*>(&we2_lds[((half*2+0)*256 + ch)*8]) = q0;
      *reinterpret_cast<short8v*>(&we2_lds[((half*2+1)*256 + ch)*8]) = q1;
      pk_lds[tid] = w2pk[tid];
    }
    __syncthreads();
    const int w = tid >> 6;                         // 8 waves
    edge_body(bid*128 + w*16, tid & 63, efeat, rij, we1b, be1, we2_lds, pk_lds, ee);
  } else if (bid < FB_EDGE + FB_FEAT){
    const int sub = tid >> 8;                       // two 32-node sub-blocks
    feat_body((bid - FB_EDGE)*2 + sub, tid & 255, nfeat, wfcb, attn_l, attn_r,
              featb, el, er);
  } else {
    const int sub = tid >> 8;
    fill_body((bid - FB_EDGE - FB_FEAT)*2 + sub, tid & 255, dst, src, fillptr, esrc);
  }
}

// ---------- SINGLE-PASS softmax+aggregation: wave per node ----------
__global__ __launch_bounds__(256) void k_sa(
    const int* __restrict__ rowptr, const int2* __restrict__ esrc,
    const float* __restrict__ el, const float* __restrict__ er,
    const float* __restrict__ ee, const short* __restrict__ featb,
    const float* __restrict__ bias, float* __restrict__ out)
{
  const int t = threadIdx.x, l = t & 63, w = t >> 6;
  const int n = blockIdx.x*4 + w;
  const int beg = rowptr[n], end = rowptr[n+1];
  const int stream = l >> 5, cl = l & 31, hh = cl >> 2;
  const float er_hh = er[(size_t)n*8 + hh];

  float acc[8];
#pragma unroll
  for (int k=0;k<8;++k) acc[k] = 0.f;
  float s = 0.f;
  for (int p = beg + stream; p < end; p += 2){
    const int2 es = esrc[p];
    const float x = ee[(size_t)es.x*8 + hh];
    float e = x + el[(size_t)es.y*8 + hh] + er_hh;
    e = e > 0.f ? e : 0.2f*e;
    const float pex = __expf(e);
    const float c = pex * x;
    s += pex;
    const short8v fv = *reinterpret_cast<const short8v*>(featb + (size_t)es.y*HD + cl*8);
#pragma unroll
    for (int k=0;k<8;++k) acc[k] = fmaf(c, b2f(fv[k]), acc[k]);
  }
  s += __shfl_xor(s, 32, 64);
#pragma unroll
  for (int k=0;k<8;++k) acc[k] += __shfl_xor(acc[k], 32, 64);
  if (l < 32){
    const float inv = (s > 0.f) ? 1.0f / s : 0.0f;
    const float4 b0 = *reinterpret_cast<const float4*>(bias + cl*8);
    const float4 b1 = *reinterpret_cast<const float4*>(bias + cl*8 + 4);
    float4 o0, o1;
    o0.x=fmaf(acc[0],inv,b0.x); o0.y=fmaf(acc[1],inv,b0.y);
    o0.z=fmaf(acc[2],inv,b0.z); o0.w=fmaf(acc[3],inv,b0.w);
    o1.x=fmaf(acc[4],inv,b1.x); o1.y=fmaf(acc[5],inv,b1.y);
    o1.z=fmaf(acc[6],inv,b1.z); o1.w=fmaf(acc[7],inv,b1.w);
    *reinterpret_cast<float4*>(out + (size_t)n*HD + cl*8) = o0;
    *reinterpret_cast<float4*>(out + (size_t)n*HD + cl*8 + 4) = o1;
  }
}

extern "C" void kernel_launch(void* const* d_in, const int* in_sizes, int n_in,
                              void* d_out, int out_size, void* d_ws, size_t ws_size,
                              hipStream_t stream) {
  const float* nfeat  = (const float*)d_in[0];
  const float* efeat  = (const float*)d_in[1];
  const float* rij    = (const float*)d_in[2];
  const int*   src    = (const int*)d_in[3];
  const int*   dst    = (const int*)d_in[4];
  const float* W_fc   = (const float*)d_in[5];
  const float* W_e1   = (const float*)d_in[6];
  const float* b_e1   = (const float*)d_in[7];
  const float* W_e2   = (const float*)d_in[8];
  const float* b_e2   = (const float*)d_in[9];
  const float* attn_l = (const float*)d_in[10];
  const float* attn_r = (const float*)d_in[11];
  const float* attn_e = (const float*)d_in[12];
  const float* bias   = (const float*)d_in[13];
  float* out = (float*)d_out;

  size_t off = 0;
  auto carve = [&](size_t nbytes) -> void* {
    void* p = (char*)d_ws + off;
    off += (nbytes + 255) & ~(size_t)255;
    return p;
  };
  short* featb = (short*)carve((size_t)NN*HD*2);
  float* el    = (float*)carve((size_t)NN*8*4);
  float* er    = (float*)carve((size_t)NN*8*4);
  float* ee    = (float*)carve((size_t)NE*8*4);
  int* deg     = (int*)carve((size_t)NN*4);
  int* rowptr  = (int*)carve((size_t)(NN+1)*4);
  int* fillptr = (int*)carve((size_t)(NN+1)*4);
  int2* esrc   = (int2*)carve((size_t)NE*8);
  int* bsum    = (int*)carve((size_t)SCAN_B*4);
  short* wfcb  = (short*)carve((size_t)HD*KIN*2);
  short* we1b  = (short*)carve((size_t)32*KIN*2);
  short* we2b  = (short*)carve((size_t)HD*32*2);
  float* w2pk  = (float*)carve((size_t)512*4);

  hipMemsetAsync(deg, 0, (size_t)NN*4, stream);
  k_cvh<<<1024, 256, 0, stream>>>(W_fc, W_e1, W_e2, b_e2, attn_e, dst,
                                  wfcb, we1b, we2b, w2pk, deg);
  k_scanA<<<SCAN_B, 1024, 0, stream>>>(deg, bsum);
  k_scanC<<<SCAN_B, 1024, 0, stream>>>(deg, bsum, rowptr, fillptr);
  k_big<<<FB_EDGE + FB_FEAT + FB_FILL, 512, 0, stream>>>(
      nfeat, wfcb, attn_l, attn_r, featb, el, er,
      dst, src, fillptr, esrc,
      efeat, rij, we1b, b_e1, we2b, w2pk, ee);
  k_sa<<<(NN+3)/4, 256, 0, stream>>>(rowptr, esrc, el, er, ee, featb, bias, out);
}